// Round 2
// baseline (6595.120 us; speedup 1.0000x reference)
//
#include <hip/hip_runtime.h>
#include <math.h>

typedef unsigned short u16;
typedef unsigned int u32;

#define Bx 1024
#define Lx 200
#define Dx 128
#define Hx 4
#define FFx 512
#define DKx 32
#define Mx (Bx*Lx)

__device__ __forceinline__ u16 f2bf(float f) {
  u32 u = __float_as_uint(f);
  u32 r = (u + 0x7fffu + ((u >> 16) & 1u)) >> 16;
  return (u16)r;
}
__device__ __forceinline__ void bf2x2(u32 u, float& lo, float& hi) {
  lo = __uint_as_float(u << 16);
  hi = __uint_as_float(u & 0xffff0000u);
}

// ---------------- embedding: x = tok[seq] + pos ----------------
__global__ void k_embed(const int* __restrict__ seq, const float* __restrict__ tok,
                        const float* __restrict__ pos, float* __restrict__ x) {
  const int i = blockIdx.x * 256 + threadIdx.x;   // float4 index, total Mx*32
  const int row = i >> 5, c = i & 31;
  const int t = seq[row];
  const int l = row % Lx;
  const float4 a = ((const float4*)tok)[(size_t)t * 32 + c];
  const float4 p = ((const float4*)pos)[l * 32 + c];
  ((float4*)x)[i] = make_float4(a.x + p.x, a.y + p.y, a.z + p.z, a.w + p.w);
}

// ---------------- fused LN + QKV + flash attention, one block per (b, head) ----------------
__global__ __launch_bounds__(256, 2)
void k_attn(const float* __restrict__ x, const int* __restrict__ seq,
            const float* __restrict__ ln_w, const float* __restrict__ ln_b,
            const float* __restrict__ Wq, const float* __restrict__ bq,
            const float* __restrict__ Wk, const float* __restrict__ bk,
            const float* __restrict__ Wv, const float* __restrict__ bv,
            u16* __restrict__ attn) {
  __shared__ union {
    u16 hs[Lx][Dx];      // bf16 bits of LN(x[b])
    float Qs[Lx * 33];   // scaled Q rows, overlaid after hs is consumed
  } U;
  __shared__ u16 Ks[Lx][DKx];
  __shared__ u16 Vs[Lx][DKx];
  __shared__ int sq[Lx];

  const int tid = threadIdx.x;
  const int b = blockIdx.x >> 2, head = blockIdx.x & 3;
  const int lane = tid & 63, wva = tid >> 6;

  // fused layernorm: one wave per row, bf16 result into LDS
  {
    float2 lw = *(const float2*)(ln_w + lane * 2);
    float2 lbv = *(const float2*)(ln_b + lane * 2);
    const float* xb = x + (size_t)b * (Lx * Dx);
    #pragma unroll 1
    for (int r = wva; r < Lx; r += 4) {
      float2 v = *(const float2*)(xb + r * Dx + lane * 2);
      float s = v.x + v.y;
      #pragma unroll
      for (int off = 32; off; off >>= 1) s += __shfl_down(s, off);
      float mu = __shfl(s, 0) * 0.0078125f;
      float dx = v.x - mu, dy = v.y - mu;
      float q = fmaf(dx, dx, dy * dy);
      #pragma unroll
      for (int off = 32; off; off >>= 1) q += __shfl_down(q, off);
      float rr = rsqrtf(fmaf(__shfl(q, 0), 0.0078125f, 1e-5f));
      u32 pk = (u32)f2bf(fmaf(dx * rr, lw.x, lbv.x)) |
               ((u32)f2bf(fmaf(dy * rr, lw.y, lbv.y)) << 16);
      *(u32*)&U.hs[r][lane * 2] = pk;
    }
  }
  if (tid < Lx) sq[tid] = seq[b * Lx + tid];
  __syncthreads();

  // compute Q,K,V: thread owns column d = tid&31 across 25 rows
  const int jb = tid >> 5;
  const int d = tid & 31;
  const int wcol = head * DKx + d;
  float aK[25], aV[25], aQ[25];
  {
    float bK = bk[wcol], bV = bv[wcol], bQ = bq[wcol];
    #pragma unroll
    for (int it = 0; it < 25; ++it) { aK[it] = bK; aV[it] = bV; aQ[it] = bQ; }
  }
  #pragma unroll 1
  for (int kb = 0; kb < 4; ++kb) {
    float wK[32], wV[32], wQ[32];
    #pragma unroll
    for (int kk = 0; kk < 32; ++kk) {
      int k = kb * 32 + kk;
      wK[kk] = Wk[k * Dx + wcol];
      wV[kk] = Wv[k * Dx + wcol];
      wQ[kk] = Wq[k * Dx + wcol];
    }
    #pragma unroll
    for (int it = 0; it < 25; ++it) {
      int j = jb + it * 8;
      #pragma unroll
      for (int kk = 0; kk < 32; kk += 4) {
        uint2 pp = *(const uint2*)&U.hs[j][kb * 32 + kk];
        float h0, h1, h2, h3;
        bf2x2(pp.x, h0, h1); bf2x2(pp.y, h2, h3);
        aK[it] = fmaf(h0, wK[kk], aK[it]);
        aV[it] = fmaf(h0, wV[kk], aV[it]);
        aQ[it] = fmaf(h0, wQ[kk], aQ[it]);
        aK[it] = fmaf(h1, wK[kk + 1], aK[it]);
        aV[it] = fmaf(h1, wV[kk + 1], aV[it]);
        aQ[it] = fmaf(h1, wQ[kk + 1], aQ[it]);
        aK[it] = fmaf(h2, wK[kk + 2], aK[it]);
        aV[it] = fmaf(h2, wV[kk + 2], aV[it]);
        aQ[it] = fmaf(h2, wQ[kk + 2], aQ[it]);
        aK[it] = fmaf(h3, wK[kk + 3], aK[it]);
        aV[it] = fmaf(h3, wV[kk + 3], aV[it]);
        aQ[it] = fmaf(h3, wQ[kk + 3], aQ[it]);
      }
    }
  }
  __syncthreads();   // all hs reads done; Qs overlay is now safe
  const float scale = 0.17677669529663687f;  // 1/sqrt(32)
  #pragma unroll
  for (int it = 0; it < 25; ++it) {
    int j = jb + it * 8;
    Ks[j][d] = f2bf(aK[it]);
    Vs[j][d] = f2bf(aV[it]);
    U.Qs[j * 33 + d] = aQ[it] * scale;
  }
  __syncthreads();

  // flash loop: one thread per query row
  if (tid < Lx) {
    float qd[32], out[32];
    #pragma unroll
    for (int d2 = 0; d2 < 32; ++d2) { qd[d2] = U.Qs[tid * 33 + d2]; out[d2] = 0.f; }
    float m = -1e30f, l = 0.f;
    #pragma unroll 1
    for (int j = 0; j < Lx; ++j) {
      float s0 = 0.f, s1 = 0.f, s2 = 0.f, s3 = 0.f;
      #pragma unroll
      for (int kk = 0; kk < 32; kk += 8) {
        uint2 p0 = *(const uint2*)&Ks[j][kk];
        uint2 p1 = *(const uint2*)&Ks[j][kk + 4];
        float k0, k1, k2, k3, k4, k5, k6, k7;
        bf2x2(p0.x, k0, k1); bf2x2(p0.y, k2, k3);
        bf2x2(p1.x, k4, k5); bf2x2(p1.y, k6, k7);
        s0 = fmaf(qd[kk], k0, s0);     s1 = fmaf(qd[kk + 1], k1, s1);
        s2 = fmaf(qd[kk + 2], k2, s2); s3 = fmaf(qd[kk + 3], k3, s3);
        s0 = fmaf(qd[kk + 4], k4, s0); s1 = fmaf(qd[kk + 5], k5, s1);
        s2 = fmaf(qd[kk + 6], k6, s2); s3 = fmaf(qd[kk + 7], k7, s3);
      }
      float s = (s0 + s1) + (s2 + s3);
      s = (sq[j] > 0) ? s : -1e9f;
      float mn = fmaxf(m, s);
      float alpha = __expf(m - mn);
      float p = __expf(s - mn);
      m = mn;
      l = fmaf(l, alpha, p);
      #pragma unroll
      for (int kk = 0; kk < 32; kk += 4) {
        uint2 pv = *(const uint2*)&Vs[j][kk];
        float v0, v1, v2, v3;
        bf2x2(pv.x, v0, v1); bf2x2(pv.y, v2, v3);
        out[kk]     = fmaf(out[kk],     alpha, p * v0);
        out[kk + 1] = fmaf(out[kk + 1], alpha, p * v1);
        out[kk + 2] = fmaf(out[kk + 2], alpha, p * v2);
        out[kk + 3] = fmaf(out[kk + 3], alpha, p * v3);
      }
    }
    float inv = 1.0f / l;
    u16* op = attn + ((size_t)b * Lx + tid) * Dx + head * DKx;
    #pragma unroll
    for (int kk = 0; kk < 32; kk += 4) {
      u32 w0 = (u32)f2bf(out[kk] * inv)     | ((u32)f2bf(out[kk + 1] * inv) << 16);
      u32 w1 = (u32)f2bf(out[kk + 2] * inv) | ((u32)f2bf(out[kk + 3] * inv) << 16);
      *(uint2*)(op + kk) = make_uint2(w0, w1);
    }
  }
}

// ---------------- O-projection + residual: x += a @ Wo + bo ----------------
__global__ __launch_bounds__(256, 4)
void k_oproj(const u16* __restrict__ a, const float* __restrict__ Wo,
             const float* __restrict__ bo, float* __restrict__ x) {
  __shared__ float as[32][132];
  const int tid = threadIdx.x;
  const size_t row0 = (size_t)blockIdx.x * 32;
  const u32* ag = (const u32*)(a + row0 * Dx);   // 32 rows * 64 u32
  #pragma unroll 1
  for (int e = tid; e < 2048; e += 256) {
    int r = e >> 6, c = (e & 63) << 1;
    float lo, hi; bf2x2(ag[e], lo, hi);
    as[r][c] = lo; as[r][c + 1] = hi;
  }
  __syncthreads();
  const int n = tid & 127;
  const int rh = (tid >> 7) << 4;
  float acc[16];
  #pragma unroll
  for (int r = 0; r < 16; ++r) acc[r] = 0.f;
  #pragma unroll 1
  for (int k = 0; k < Dx; k += 4) {
    float w0 = Wo[(k + 0) * Dx + n];
    float w1 = Wo[(k + 1) * Dx + n];
    float w2 = Wo[(k + 2) * Dx + n];
    float w3 = Wo[(k + 3) * Dx + n];
    #pragma unroll
    for (int r = 0; r < 16; ++r) {
      float4 av = *(const float4*)&as[rh + r][k];
      acc[r] = fmaf(av.x, w0, acc[r]);
      acc[r] = fmaf(av.y, w1, acc[r]);
      acc[r] = fmaf(av.z, w2, acc[r]);
      acc[r] = fmaf(av.w, w3, acc[r]);
    }
  }
  const float bn = bo[n];
  #pragma unroll
  for (int r = 0; r < 16; ++r) {
    size_t idx = (row0 + rh + r) * Dx + n;
    x[idx] += acc[r] + bn;
  }
}

// ---------------- fused LN + FFN: x += gelu(LN(x)@W1+b1)@W2 + b2 ----------------
__global__ __launch_bounds__(256, 4)
void k_ffn(float* __restrict__ x, const float* __restrict__ ln_w,
           const float* __restrict__ ln_b,
           const float* __restrict__ W1, const float* __restrict__ b1,
           const float* __restrict__ W2, const float* __restrict__ b2) {
  __shared__ float hs[32][132];
  __shared__ float ts[32][68];
  const int tid = threadIdx.x;
  const size_t row0 = (size_t)blockIdx.x * 32;
  const int lane = tid & 63, wva = tid >> 6;

  // fused layernorm: one wave per row
  {
    float2 lw = *(const float2*)(ln_w + lane * 2);
    float2 lbv = *(const float2*)(ln_b + lane * 2);
    #pragma unroll 1
    for (int r = wva; r < 32; r += 4) {
      float2 v = *(const float2*)(x + (row0 + r) * Dx + lane * 2);
      float s = v.x + v.y;
      #pragma unroll
      for (int off = 32; off; off >>= 1) s += __shfl_down(s, off);
      float mu = __shfl(s, 0) * 0.0078125f;
      float dx = v.x - mu, dy = v.y - mu;
      float q = fmaf(dx, dx, dy * dy);
      #pragma unroll
      for (int off = 32; off; off >>= 1) q += __shfl_down(q, off);
      float rr = rsqrtf(fmaf(__shfl(q, 0), 0.0078125f, 1e-5f));
      hs[r][lane * 2]     = fmaf(dx * rr, lw.x, lbv.x);
      hs[r][lane * 2 + 1] = fmaf(dy * rr, lw.y, lbv.y);
    }
  }
  const int n = tid & 127;
  const int rh = (tid >> 7) << 4;
  const int tr = tid >> 3;          // row for t-compute
  const int tf = (tid & 7) << 3;    // f-group base (8 wide)
  float acc[16];
  #pragma unroll
  for (int r = 0; r < 16; ++r) acc[r] = 0.f;
  __syncthreads();
  #pragma unroll 1
  for (int ch = 0; ch < 8; ++ch) {
    const int F0 = ch * 64;
    float t8[8];
    #pragma unroll
    for (int jj = 0; jj < 8; ++jj) t8[jj] = b1[F0 + tf + jj];
    #pragma unroll 2
    for (int k = 0; k < Dx; ++k) {
      float hvs = hs[tr][k];
      const float* wrow = &W1[k * FFx + F0 + tf];
      float4 wa = *(const float4*)wrow;
      float4 wb = *(const float4*)(wrow + 4);
      t8[0] = fmaf(hvs, wa.x, t8[0]);
      t8[1] = fmaf(hvs, wa.y, t8[1]);
      t8[2] = fmaf(hvs, wa.z, t8[2]);
      t8[3] = fmaf(hvs, wa.w, t8[3]);
      t8[4] = fmaf(hvs, wb.x, t8[4]);
      t8[5] = fmaf(hvs, wb.y, t8[5]);
      t8[6] = fmaf(hvs, wb.z, t8[6]);
      t8[7] = fmaf(hvs, wb.w, t8[7]);
    }
    #pragma unroll
    for (int jj = 0; jj < 8; ++jj) {
      float v = t8[jj];
      t8[jj] = 0.5f * v * (1.0f + erff(v * 0.70710678118654752f));
    }
    __syncthreads();
    *(float4*)&ts[tr][tf]     = make_float4(t8[0], t8[1], t8[2], t8[3]);
    *(float4*)&ts[tr][tf + 4] = make_float4(t8[4], t8[5], t8[6], t8[7]);
    __syncthreads();
    #pragma unroll 1
    for (int f4 = 0; f4 < 16; ++f4) {
      const int f = F0 + (f4 << 2);
      float w0 = W2[(f + 0) * Dx + n];
      float w1 = W2[(f + 1) * Dx + n];
      float w2 = W2[(f + 2) * Dx + n];
      float w3 = W2[(f + 3) * Dx + n];
      #pragma unroll
      for (int r = 0; r < 16; ++r) {
        float4 tv = *(const float4*)&ts[rh + r][f4 << 2];
        acc[r] = fmaf(tv.x, w0, acc[r]);
        acc[r] = fmaf(tv.y, w1, acc[r]);
        acc[r] = fmaf(tv.z, w2, acc[r]);
        acc[r] = fmaf(tv.w, w3, acc[r]);
      }
    }
  }
  const float bn = b2[n];
  #pragma unroll
  for (int r = 0; r < 16; ++r) {
    size_t idx = (row0 + rh + r) * Dx + n;
    x[idx] += acc[r] + bn;
  }
}

// ---------------- final FC, split-K partials ----------------
__global__ __launch_bounds__(256, 4)
void k_fc(const float* __restrict__ x, const float* __restrict__ Wf,
          float* __restrict__ part) {
  __shared__ float xs[16][324];
  const int tid = threadIdx.x;
  const int b0 = blockIdx.x * 16;
  const int n = tid & 127;
  const int half = tid >> 7;
  float acc[16];
  #pragma unroll
  for (int r = 0; r < 16; ++r) acc[r] = 0.f;
  #pragma unroll 1
  for (int ch = 0; ch < 10; ++ch) {
    const int k0 = blockIdx.y * 3200 + ch * 320;
    __syncthreads();
    #pragma unroll 1
    for (int e = tid; e < 1280; e += 256) {
      int r = e / 80, c = (e - r * 80) << 2;
      *(float4*)&xs[r][c] = *(const float4*)&x[(size_t)(b0 + r) * 25600 + k0 + c];
    }
    __syncthreads();
    const int kb = half * 160;
    #pragma unroll 1
    for (int i4 = 0; i4 < 40; ++i4) {
      const int kk = kb + (i4 << 2);
      const float* wp = &Wf[(size_t)(k0 + kk) * Dx + n];
      float w0 = wp[0], w1 = wp[Dx], w2 = wp[2 * Dx], w3 = wp[3 * Dx];
      #pragma unroll
      for (int r = 0; r < 16; ++r) {
        float4 xv = *(const float4*)&xs[r][kk];
        acc[r] = fmaf(xv.x, w0, acc[r]);
        acc[r] = fmaf(xv.y, w1, acc[r]);
        acc[r] = fmaf(xv.z, w2, acc[r]);
        acc[r] = fmaf(xv.w, w3, acc[r]);
      }
    }
  }
  float* pp = part + (size_t)(blockIdx.y * 2 + half) * (Bx * Dx);
  #pragma unroll
  for (int r = 0; r < 16; ++r) pp[(b0 + r) * Dx + n] = acc[r];
}

__global__ void k_fcred(const float* __restrict__ part, const float* __restrict__ fcb,
                        float* __restrict__ out) {
  int i = blockIdx.x * 256 + threadIdx.x;
  float s = fcb[i & 127];
  #pragma unroll
  for (int k = 0; k < 16; ++k) s += part[(size_t)k * (Bx * Dx) + i];
  out[i] = s;
}

extern "C" void kernel_launch(void* const* d_in, const int* in_sizes, int n_in,
                              void* d_out, int out_size, void* d_ws, size_t ws_size,
                              hipStream_t stream) {
  const int*   seq  = (const int*)d_in[0];
  const float* tok  = (const float*)d_in[1];
  const float* pos  = (const float*)d_in[2];
  const float* Wq   = (const float*)d_in[3];
  const float* bq   = (const float*)d_in[4];
  const float* Wk   = (const float*)d_in[5];
  const float* bk   = (const float*)d_in[6];
  const float* Wv   = (const float*)d_in[7];
  const float* bv   = (const float*)d_in[8];
  const float* Wo   = (const float*)d_in[9];
  const float* bo   = (const float*)d_in[10];
  const float* ln1w = (const float*)d_in[11];
  const float* ln1b = (const float*)d_in[12];
  const float* ln2w = (const float*)d_in[13];
  const float* ln2b = (const float*)d_in[14];
  const float* W1   = (const float*)d_in[15];
  const float* b1   = (const float*)d_in[16];
  const float* W2   = (const float*)d_in[17];
  const float* b2   = (const float*)d_in[18];
  const float* fcW  = (const float*)d_in[19];
  const float* fcb  = (const float*)d_in[20];
  float* out = (float*)d_out;

  char* ws = (char*)d_ws;
  const size_t XB = (size_t)Mx * Dx * 4;      // 104,857,600 B
  float* x     = (float*)ws;                  // [0, XB)
  u16*   attnb = (u16*)(ws + XB);             // [XB, XB + XB/2) bf16
  float* part  = (float*)(ws + XB);           // FC partials alias attn region

  k_embed<<<25600, 256, 0, stream>>>(seq, tok, pos, x);
  for (int i = 0; i < 2; ++i) {
    k_attn<<<4096, 256, 0, stream>>>(x, seq,
                                     ln1w + i * Dx, ln1b + i * Dx,
                                     Wq + i * Dx * Dx, bq + i * Dx,
                                     Wk + i * Dx * Dx, bk + i * Dx,
                                     Wv + i * Dx * Dx, bv + i * Dx, attnb);
    k_oproj<<<6400, 256, 0, stream>>>(attnb, Wo + i * Dx * Dx, bo + i * Dx, x);
    k_ffn<<<6400, 256, 0, stream>>>(x, ln2w + i * Dx, ln2b + i * Dx,
                                    W1 + i * Dx * FFx, b1 + i * FFx,
                                    W2 + i * FFx * Dx, b2 + i * Dx);
  }
  k_fc<<<dim3(64, 8), 256, 0, stream>>>(x, fcW, part);
  k_fcred<<<512, 256, 0, stream>>>(part, fcb, out);
}

// Round 3
// 3415.307 us; speedup vs baseline: 1.9310x; 1.9310x over previous
//
#include <hip/hip_runtime.h>
#include <math.h>

typedef unsigned short u16;
typedef unsigned int u32;
typedef __attribute__((ext_vector_type(8))) short bf16x8;
typedef __attribute__((ext_vector_type(4))) float f32x4;

#define Bx 1024
#define Lx 200
#define Dx 128
#define Hx 4
#define FFx 512
#define DKx 32
#define Mx (Bx*Lx)
#define LNP 136   // padded LDS row stride (u16), 272B: 16B-aligned, 2-way-bank-free

__device__ __forceinline__ u16 f2bf(float f) {
  u32 u = __float_as_uint(f);
  u32 r = (u + 0x7fffu + ((u >> 16) & 1u)) >> 16;
  return (u16)r;
}
__device__ __forceinline__ void bf2x2(u32 u, float& lo, float& hi) {
  lo = __uint_as_float(u << 16);
  hi = __uint_as_float(u & 0xffff0000u);
}

// ---------------- weight convert: fp32 [K][N] -> bf16 fragment order ----------------
// dst layout: [n_tile][k_step][lane][8], value = src[kst*32 + (lane>>4)*8 + j][ntile*16 + (lane&15)]
__global__ void k_cvt(const float* __restrict__ src, u16* __restrict__ dst,
                      int N, int k_steps) {
  int id = blockIdx.x * 256 + threadIdx.x;
  int lane = id & 63;
  int rest = id >> 6;
  int kst = rest % k_steps;
  int ntile = rest / k_steps;
  int n = ntile * 16 + (lane & 15);
  int kb = kst * 32 + ((lane >> 4) << 3);
  const float* sp = src + (size_t)kb * N + n;
  u32 w[4];
  #pragma unroll
  for (int j = 0; j < 4; ++j) {
    u32 lo = f2bf(sp[(size_t)(2 * j) * N]);
    u32 hi = f2bf(sp[(size_t)(2 * j + 1) * N]);
    w[j] = lo | (hi << 16);
  }
  ((uint4*)dst)[id] = make_uint4(w[0], w[1], w[2], w[3]);
}

// ---------------- embedding: x = tok[seq] + pos ----------------
__global__ void k_embed(const int* __restrict__ seq, const float* __restrict__ tok,
                        const float* __restrict__ pos, float* __restrict__ x) {
  const int i = blockIdx.x * 256 + threadIdx.x;
  const int row = i >> 5, c = i & 31;
  const int t = seq[row];
  const int l = row % Lx;
  const float4 a = ((const float4*)tok)[(size_t)t * 32 + c];
  const float4 p = ((const float4*)pos)[l * 32 + c];
  ((float4*)x)[i] = make_float4(a.x + p.x, a.y + p.y, a.z + p.z, a.w + p.w);
}

// ---------------- fused LN + QKV + flash attention (unchanged from r2) ----------------
__global__ __launch_bounds__(256, 2)
void k_attn(const float* __restrict__ x, const int* __restrict__ seq,
            const float* __restrict__ ln_w, const float* __restrict__ ln_b,
            const float* __restrict__ Wq, const float* __restrict__ bq,
            const float* __restrict__ Wk, const float* __restrict__ bk,
            const float* __restrict__ Wv, const float* __restrict__ bv,
            u16* __restrict__ attn) {
  __shared__ union {
    u16 hs[Lx][Dx];
    float Qs[Lx * 33];
  } U;
  __shared__ u16 Ks[Lx][DKx];
  __shared__ u16 Vs[Lx][DKx];
  __shared__ int sq[Lx];

  const int tid = threadIdx.x;
  const int b = blockIdx.x >> 2, head = blockIdx.x & 3;
  const int lane = tid & 63, wva = tid >> 6;

  {
    float2 lw = *(const float2*)(ln_w + lane * 2);
    float2 lbv = *(const float2*)(ln_b + lane * 2);
    const float* xb = x + (size_t)b * (Lx * Dx);
    #pragma unroll 1
    for (int r = wva; r < Lx; r += 4) {
      float2 v = *(const float2*)(xb + r * Dx + lane * 2);
      float s = v.x + v.y;
      #pragma unroll
      for (int off = 32; off; off >>= 1) s += __shfl_down(s, off);
      float mu = __shfl(s, 0) * 0.0078125f;
      float dx = v.x - mu, dy = v.y - mu;
      float q = fmaf(dx, dx, dy * dy);
      #pragma unroll
      for (int off = 32; off; off >>= 1) q += __shfl_down(q, off);
      float rr = rsqrtf(fmaf(__shfl(q, 0), 0.0078125f, 1e-5f));
      u32 pk = (u32)f2bf(fmaf(dx * rr, lw.x, lbv.x)) |
               ((u32)f2bf(fmaf(dy * rr, lw.y, lbv.y)) << 16);
      *(u32*)&U.hs[r][lane * 2] = pk;
    }
  }
  if (tid < Lx) sq[tid] = seq[b * Lx + tid];
  __syncthreads();

  const int jb = tid >> 5;
  const int d = tid & 31;
  const int wcol = head * DKx + d;
  float aK[25], aV[25], aQ[25];
  {
    float bK = bk[wcol], bV = bv[wcol], bQ = bq[wcol];
    #pragma unroll
    for (int it = 0; it < 25; ++it) { aK[it] = bK; aV[it] = bV; aQ[it] = bQ; }
  }
  #pragma unroll 1
  for (int kb = 0; kb < 4; ++kb) {
    float wK[32], wV[32], wQ[32];
    #pragma unroll
    for (int kk = 0; kk < 32; ++kk) {
      int k = kb * 32 + kk;
      wK[kk] = Wk[k * Dx + wcol];
      wV[kk] = Wv[k * Dx + wcol];
      wQ[kk] = Wq[k * Dx + wcol];
    }
    #pragma unroll
    for (int it = 0; it < 25; ++it) {
      int j = jb + it * 8;
      #pragma unroll
      for (int kk = 0; kk < 32; kk += 4) {
        uint2 pp = *(const uint2*)&U.hs[j][kb * 32 + kk];
        float h0, h1, h2, h3;
        bf2x2(pp.x, h0, h1); bf2x2(pp.y, h2, h3);
        aK[it] = fmaf(h0, wK[kk], aK[it]);
        aV[it] = fmaf(h0, wV[kk], aV[it]);
        aQ[it] = fmaf(h0, wQ[kk], aQ[it]);
        aK[it] = fmaf(h1, wK[kk + 1], aK[it]);
        aV[it] = fmaf(h1, wV[kk + 1], aV[it]);
        aQ[it] = fmaf(h1, wQ[kk + 1], aQ[it]);
        aK[it] = fmaf(h2, wK[kk + 2], aK[it]);
        aV[it] = fmaf(h2, wV[kk + 2], aV[it]);
        aQ[it] = fmaf(h2, wQ[kk + 2], aQ[it]);
        aK[it] = fmaf(h3, wK[kk + 3], aK[it]);
        aV[it] = fmaf(h3, wV[kk + 3], aV[it]);
        aQ[it] = fmaf(h3, wQ[kk + 3], aQ[it]);
      }
    }
  }
  __syncthreads();
  const float scale = 0.17677669529663687f;
  #pragma unroll
  for (int it = 0; it < 25; ++it) {
    int j = jb + it * 8;
    Ks[j][d] = f2bf(aK[it]);
    Vs[j][d] = f2bf(aV[it]);
    U.Qs[j * 33 + d] = aQ[it] * scale;
  }
  __syncthreads();

  if (tid < Lx) {
    float qd[32], out[32];
    #pragma unroll
    for (int d2 = 0; d2 < 32; ++d2) { qd[d2] = U.Qs[tid * 33 + d2]; out[d2] = 0.f; }
    float m = -1e30f, l = 0.f;
    #pragma unroll 1
    for (int j = 0; j < Lx; ++j) {
      float s0 = 0.f, s1 = 0.f, s2 = 0.f, s3 = 0.f;
      #pragma unroll
      for (int kk = 0; kk < 32; kk += 8) {
        uint2 p0 = *(const uint2*)&Ks[j][kk];
        uint2 p1 = *(const uint2*)&Ks[j][kk + 4];
        float k0, k1, k2, k3, k4, k5, k6, k7;
        bf2x2(p0.x, k0, k1); bf2x2(p0.y, k2, k3);
        bf2x2(p1.x, k4, k5); bf2x2(p1.y, k6, k7);
        s0 = fmaf(qd[kk], k0, s0);     s1 = fmaf(qd[kk + 1], k1, s1);
        s2 = fmaf(qd[kk + 2], k2, s2); s3 = fmaf(qd[kk + 3], k3, s3);
        s0 = fmaf(qd[kk + 4], k4, s0); s1 = fmaf(qd[kk + 5], k5, s1);
        s2 = fmaf(qd[kk + 6], k6, s2); s3 = fmaf(qd[kk + 7], k7, s3);
      }
      float s = (s0 + s1) + (s2 + s3);
      s = (sq[j] > 0) ? s : -1e9f;
      float mn = fmaxf(m, s);
      float alpha = __expf(m - mn);
      float p = __expf(s - mn);
      m = mn;
      l = fmaf(l, alpha, p);
      #pragma unroll
      for (int kk = 0; kk < 32; kk += 4) {
        uint2 pv = *(const uint2*)&Vs[j][kk];
        float v0, v1, v2, v3;
        bf2x2(pv.x, v0, v1); bf2x2(pv.y, v2, v3);
        out[kk]     = fmaf(out[kk],     alpha, p * v0);
        out[kk + 1] = fmaf(out[kk + 1], alpha, p * v1);
        out[kk + 2] = fmaf(out[kk + 2], alpha, p * v2);
        out[kk + 3] = fmaf(out[kk + 3], alpha, p * v3);
      }
    }
    float inv = 1.0f / l;
    u16* op = attn + ((size_t)b * Lx + tid) * Dx + head * DKx;
    #pragma unroll
    for (int kk = 0; kk < 32; kk += 4) {
      u32 w0 = (u32)f2bf(out[kk] * inv)     | ((u32)f2bf(out[kk + 1] * inv) << 16);
      u32 w1 = (u32)f2bf(out[kk + 2] * inv) | ((u32)f2bf(out[kk + 3] * inv) << 16);
      *(uint2*)(op + kk) = make_uint2(w0, w1);
    }
  }
}

// ---------------- O-projection + residual (MFMA): x += a @ Wo + bo ----------------
__global__ __launch_bounds__(256, 4)
void k_oproj(const u16* __restrict__ a, const u16* __restrict__ Wos,
             const float* __restrict__ bo, float* __restrict__ x) {
  const int tid = threadIdx.x;
  const int lane = tid & 63, wv = tid >> 6;
  const int l15 = lane & 15, quad = lane >> 4;
  const size_t m0 = (size_t)blockIdx.x * 64 + wv * 16;
  f32x4 acc[8];
  #pragma unroll
  for (int i = 0; i < 8; ++i) acc[i] = (f32x4){0.f, 0.f, 0.f, 0.f};
  #pragma unroll
  for (int kst = 0; kst < 4; ++kst) {
    bf16x8 af = *(const bf16x8*)(a + (m0 + l15) * Dx + kst * 32 + quad * 8);
    const u16* wb = Wos + (kst * 64 + lane) * 8;
    #pragma unroll
    for (int nt = 0; nt < 8; ++nt) {
      bf16x8 bf = *(const bf16x8*)(wb + nt * (4 * 64 * 8));
      acc[nt] = __builtin_amdgcn_mfma_f32_16x16x32_bf16(af, bf, acc[nt], 0, 0, 0);
    }
  }
  #pragma unroll
  for (int nt = 0; nt < 8; ++nt) {
    int col = nt * 16 + l15;
    float bb = bo[col];
    #pragma unroll
    for (int r = 0; r < 4; ++r) {
      size_t idx = (m0 + quad * 4 + r) * Dx + col;
      x[idx] += acc[nt][r] + bb;
    }
  }
}

// ---------------- fused LN + FFN (MFMA): x += gelu(LN(x)@W1+b1)@W2 + b2 ----------------
__global__ __launch_bounds__(256, 2)
void k_ffn(float* __restrict__ x, const float* __restrict__ ln_w,
           const float* __restrict__ ln_b,
           const u16* __restrict__ W1s, const float* __restrict__ b1,
           const u16* __restrict__ W2s, const float* __restrict__ b2) {
  __shared__ u16 hs[64][LNP];
  __shared__ u16 ts[64][LNP];
  const int tid = threadIdx.x;
  const size_t row0 = (size_t)blockIdx.x * 64;
  const int lane = tid & 63, wv = tid >> 6;

  // fused layernorm -> hs (bf16)
  {
    float2 lw = *(const float2*)(ln_w + lane * 2);
    float2 lbv = *(const float2*)(ln_b + lane * 2);
    #pragma unroll 1
    for (int r = wv; r < 64; r += 4) {
      float2 v = *(const float2*)(x + (row0 + r) * Dx + lane * 2);
      float s = v.x + v.y;
      #pragma unroll
      for (int off = 32; off; off >>= 1) s += __shfl_down(s, off);
      float mu = __shfl(s, 0) * 0.0078125f;
      float dx = v.x - mu, dy = v.y - mu;
      float q = fmaf(dx, dx, dy * dy);
      #pragma unroll
      for (int off = 32; off; off >>= 1) q += __shfl_down(q, off);
      float rr = rsqrtf(fmaf(__shfl(q, 0), 0.0078125f, 1e-5f));
      u32 pk = (u32)f2bf(fmaf(dx * rr, lw.x, lbv.x)) |
               ((u32)f2bf(fmaf(dy * rr, lw.y, lbv.y)) << 16);
      *(u32*)&hs[r][lane * 2] = pk;
    }
  }
  __syncthreads();

  const int l15 = lane & 15, quad = lane >> 4;
  const int m0 = wv * 16;
  f32x4 acc2[8];
  #pragma unroll
  for (int i = 0; i < 8; ++i) acc2[i] = (f32x4){0.f, 0.f, 0.f, 0.f};

  #pragma unroll 1
  for (int ch = 0; ch < 4; ++ch) {
    f32x4 acc1[8];
    #pragma unroll
    for (int i = 0; i < 8; ++i) acc1[i] = (f32x4){0.f, 0.f, 0.f, 0.f};
    #pragma unroll
    for (int kst = 0; kst < 4; ++kst) {
      bf16x8 af = *(const bf16x8*)&hs[m0 + l15][kst * 32 + quad * 8];
      const u16* wb = W1s + (((ch * 8) * 4 + kst) * 64 + lane) * 8;
      #pragma unroll
      for (int nt = 0; nt < 8; ++nt) {
        bf16x8 bf = *(const bf16x8*)(wb + nt * (4 * 64 * 8));
        acc1[nt] = __builtin_amdgcn_mfma_f32_16x16x32_bf16(af, bf, acc1[nt], 0, 0, 0);
      }
    }
    __syncthreads();   // prev chunk's GEMM2 reads of ts are done
    #pragma unroll
    for (int nt = 0; nt < 8; ++nt) {
      int col = nt * 16 + l15;
      float bb = b1[ch * 128 + col];
      #pragma unroll
      for (int r = 0; r < 4; ++r) {
        float v = acc1[nt][r] + bb;
        v = 0.5f * v * (1.0f + erff(v * 0.70710678118654752f));
        ts[m0 + quad * 4 + r][col] = f2bf(v);
      }
    }
    __syncthreads();   // ts visible
    #pragma unroll
    for (int kst = 0; kst < 4; ++kst) {
      bf16x8 af = *(const bf16x8*)&ts[m0 + l15][kst * 32 + quad * 8];
      const u16* wb = W2s + ((ch * 4 + kst) * 64 + lane) * 8;
      #pragma unroll
      for (int nt = 0; nt < 8; ++nt) {
        bf16x8 bf = *(const bf16x8*)(wb + nt * (16 * 64 * 8));
        acc2[nt] = __builtin_amdgcn_mfma_f32_16x16x32_bf16(af, bf, acc2[nt], 0, 0, 0);
      }
    }
  }
  #pragma unroll
  for (int nt = 0; nt < 8; ++nt) {
    int col = nt * 16 + l15;
    float bb = b2[col];
    #pragma unroll
    for (int r = 0; r < 4; ++r) {
      size_t idx = (row0 + m0 + quad * 4 + r) * Dx + col;
      x[idx] += acc2[nt][r] + bb;
    }
  }
}

// ---------------- final FC (MFMA, split-K 32): part[ky] = x_chunk @ fcW_chunk ----------------
__global__ __launch_bounds__(256, 4)
void k_fc(const float* __restrict__ x, const u16* __restrict__ fcWs,
          float* __restrict__ part) {
  const int tid = threadIdx.x;
  const int lane = tid & 63, wv = tid >> 6;
  const int l15 = lane & 15, quad = lane >> 4;
  const int m0 = blockIdx.x * 64 + wv * 16;
  const int ky = blockIdx.y;
  f32x4 acc[8];
  #pragma unroll
  for (int i = 0; i < 8; ++i) acc[i] = (f32x4){0.f, 0.f, 0.f, 0.f};
  const float* xp = x + (size_t)(m0 + l15) * 25600 + quad * 8;
  #pragma unroll 1
  for (int kst = ky * 25; kst < ky * 25 + 25; ++kst) {
    float4 xa = *(const float4*)(xp + kst * 32);
    float4 xb2 = *(const float4*)(xp + kst * 32 + 4);
    bf16x8 af;
    af[0] = (short)f2bf(xa.x);  af[1] = (short)f2bf(xa.y);
    af[2] = (short)f2bf(xa.z);  af[3] = (short)f2bf(xa.w);
    af[4] = (short)f2bf(xb2.x); af[5] = (short)f2bf(xb2.y);
    af[6] = (short)f2bf(xb2.z); af[7] = (short)f2bf(xb2.w);
    const u16* wb = fcWs + ((size_t)kst * 64 + lane) * 8;
    #pragma unroll
    for (int nt = 0; nt < 8; ++nt) {
      bf16x8 bf = *(const bf16x8*)(wb + (size_t)nt * (800 * 64 * 8));
      acc[nt] = __builtin_amdgcn_mfma_f32_16x16x32_bf16(af, bf, acc[nt], 0, 0, 0);
    }
  }
  float* pp = part + (size_t)ky * (Bx * Dx);
  #pragma unroll
  for (int nt = 0; nt < 8; ++nt) {
    #pragma unroll
    for (int r = 0; r < 4; ++r) {
      pp[(size_t)(m0 + quad * 4 + r) * Dx + nt * 16 + l15] = acc[nt][r];
    }
  }
}

__global__ void k_fcred(const float* __restrict__ part, const float* __restrict__ fcb,
                        float* __restrict__ out) {
  int i = blockIdx.x * 256 + threadIdx.x;
  float s = fcb[i & 127];
  #pragma unroll
  for (int k = 0; k < 32; ++k) s += part[(size_t)k * (Bx * Dx) + i];
  out[i] = s;
}

extern "C" void kernel_launch(void* const* d_in, const int* in_sizes, int n_in,
                              void* d_out, int out_size, void* d_ws, size_t ws_size,
                              hipStream_t stream) {
  const int*   seq  = (const int*)d_in[0];
  const float* tok  = (const float*)d_in[1];
  const float* pos  = (const float*)d_in[2];
  const float* Wq   = (const float*)d_in[3];
  const float* bq   = (const float*)d_in[4];
  const float* Wk   = (const float*)d_in[5];
  const float* bk   = (const float*)d_in[6];
  const float* Wv   = (const float*)d_in[7];
  const float* bv   = (const float*)d_in[8];
  const float* Wo   = (const float*)d_in[9];
  const float* bo   = (const float*)d_in[10];
  const float* ln1w = (const float*)d_in[11];
  const float* ln1b = (const float*)d_in[12];
  const float* ln2w = (const float*)d_in[13];
  const float* ln2b = (const float*)d_in[14];
  const float* W1   = (const float*)d_in[15];
  const float* b1   = (const float*)d_in[16];
  const float* W2   = (const float*)d_in[17];
  const float* b2   = (const float*)d_in[18];
  const float* fcW  = (const float*)d_in[19];
  const float* fcb  = (const float*)d_in[20];
  float* out = (float*)d_out;

  char* ws = (char*)d_ws;
  const size_t XB = (size_t)Mx * Dx * 4;          // 104,857,600 B
  float* x     = (float*)ws;                      // [0, XB)
  u16*   attnb = (u16*)(ws + XB);                 // bf16 attn, 52.4 MB
  float* part  = (float*)(ws + XB);               // FC partials alias attn (dead by then)
  char*  WB    = ws + XB + XB / 2;                // converted weights, ~7.1 MB
  u16* W1s0 = (u16*)(WB);
  u16* W1s1 = (u16*)(WB + 131072);
  u16* W2s0 = (u16*)(WB + 262144);
  u16* W2s1 = (u16*)(WB + 393216);
  u16* Wos0 = (u16*)(WB + 524288);
  u16* Wos1 = (u16*)(WB + 557056);
  u16* fcWs = (u16*)(WB + 589824);

  // weight conversion to fragment-ordered bf16
  k_cvt<<<32, 256, 0, stream>>>(W1, W1s0, FFx, 4);
  k_cvt<<<32, 256, 0, stream>>>(W1 + Dx * FFx, W1s1, FFx, 4);
  k_cvt<<<32, 256, 0, stream>>>(W2, W2s0, Dx, 16);
  k_cvt<<<32, 256, 0, stream>>>(W2 + FFx * Dx, W2s1, Dx, 16);
  k_cvt<<<8, 256, 0, stream>>>(Wo, Wos0, Dx, 4);
  k_cvt<<<8, 256, 0, stream>>>(Wo + Dx * Dx, Wos1, Dx, 4);
  k_cvt<<<1600, 256, 0, stream>>>(fcW, fcWs, Dx, 800);

  k_embed<<<25600, 256, 0, stream>>>(seq, tok, pos, x);
  for (int i = 0; i < 2; ++i) {
    k_attn<<<4096, 256, 0, stream>>>(x, seq,
                                     ln1w + i * Dx, ln1b + i * Dx,
                                     Wq + i * Dx * Dx, bq + i * Dx,
                                     Wk + i * Dx * Dx, bk + i * Dx,
                                     Wv + i * Dx * Dx, bv + i * Dx, attnb);
    k_oproj<<<3200, 256, 0, stream>>>(attnb, (i == 0) ? Wos0 : Wos1, bo + i * Dx, x);
    k_ffn<<<3200, 256, 0, stream>>>(x, ln2w + i * Dx, ln2b + i * Dx,
                                    (i == 0) ? W1s0 : W1s1, b1 + i * FFx,
                                    (i == 0) ? W2s0 : W2s1, b2 + i * Dx);
  }
  k_fc<<<dim3(16, 32), 256, 0, stream>>>(x, fcWs, part);
  k_fcred<<<512, 256, 0, stream>>>(part, fcb, out);
}

// Round 4
// 1243.608 us; speedup vs baseline: 5.3032x; 2.7463x over previous
//
#include <hip/hip_runtime.h>
#include <math.h>

typedef unsigned short u16;
typedef unsigned int u32;
typedef __attribute__((ext_vector_type(8))) short bf16x8;
typedef __attribute__((ext_vector_type(4))) float f32x4;

#define Bx 1024
#define Lx 200
#define Dx 128
#define FFx 512
#define Mx (Bx*Lx)
#define LNP 136   // padded LDS row stride (u16)
#define PVP 232   // P/V^T LDS row stride (u16): 116 words, l15*116%32=l15*20 -> ~2-way

__device__ __forceinline__ u16 f2bf(float f) {
  u32 u = __float_as_uint(f);
  u32 r = (u + 0x7fffu + ((u >> 16) & 1u)) >> 16;
  return (u16)r;
}

// ---------------- weight convert: fp32 [K][N] -> bf16 fragment order ----------------
// dst: [n_tile][k_step][lane][8], val = src[kst*32 + (lane>>4)*8 + j][ntile*16 + (lane&15)]
__global__ void k_cvt(const float* __restrict__ src, u16* __restrict__ dst,
                      int N, int k_steps) {
  int id = blockIdx.x * 256 + threadIdx.x;
  int lane = id & 63;
  int rest = id >> 6;
  int kst = rest % k_steps;
  int ntile = rest / k_steps;
  int n = ntile * 16 + (lane & 15);
  int kb = kst * 32 + ((lane >> 4) << 3);
  const float* sp = src + (size_t)kb * N + n;
  u32 w[4];
  #pragma unroll
  for (int j = 0; j < 4; ++j) {
    u32 lo = f2bf(sp[(size_t)(2 * j) * N]);
    u32 hi = f2bf(sp[(size_t)(2 * j + 1) * N]);
    w[j] = lo | (hi << 16);
  }
  ((uint4*)dst)[id] = make_uint4(w[0], w[1], w[2], w[3]);
}

// ---------------- embedding: x = tok[seq] + pos ----------------
__global__ void k_embed(const int* __restrict__ seq, const float* __restrict__ tok,
                        const float* __restrict__ pos, float* __restrict__ x) {
  const int i = blockIdx.x * 256 + threadIdx.x;
  const int row = i >> 5, c = i & 31;
  const int t = seq[row];
  const int l = row % Lx;
  const float4 a = ((const float4*)tok)[(size_t)t * 32 + c];
  const float4 p = ((const float4*)pos)[l * 32 + c];
  ((float4*)x)[i] = make_float4(a.x + p.x, a.y + p.y, a.z + p.z, a.w + p.w);
}

// ---------------- fused LN + QKV GEMM (MFMA) ----------------
// x: chunk base (fp32). q/k/v out: [b_local][head][l][32] bf16. Q pre-scaled by 1/sqrt(32).
__global__ __launch_bounds__(256, 3)
void k_qkv(const float* __restrict__ x, const float* __restrict__ ln_w,
           const float* __restrict__ ln_b, const u16* __restrict__ Wqkvs,
           const float* __restrict__ bq, const float* __restrict__ bk,
           const float* __restrict__ bv,
           u16* __restrict__ qo, u16* __restrict__ ko, u16* __restrict__ vo) {
  __shared__ u16 hs[64][LNP];
  const int tid = threadIdx.x;
  const int row0 = blockIdx.x * 64;
  const int lane = tid & 63, wv = tid >> 6;

  { // layernorm -> hs (bf16), one wave per row
    float2 lw = *(const float2*)(ln_w + lane * 2);
    float2 lbv = *(const float2*)(ln_b + lane * 2);
    #pragma unroll 1
    for (int r = wv; r < 64; r += 4) {
      float2 vx = *(const float2*)(x + (size_t)(row0 + r) * Dx + lane * 2);
      float s = vx.x + vx.y;
      #pragma unroll
      for (int off = 32; off; off >>= 1) s += __shfl_down(s, off);
      float mu = __shfl(s, 0) * 0.0078125f;
      float dx = vx.x - mu, dy = vx.y - mu;
      float qq = fmaf(dx, dx, dy * dy);
      #pragma unroll
      for (int off = 32; off; off >>= 1) qq += __shfl_down(qq, off);
      float rr = rsqrtf(fmaf(__shfl(qq, 0), 0.0078125f, 1e-5f));
      u32 pk = (u32)f2bf(fmaf(dx * rr, lw.x, lbv.x)) |
               ((u32)f2bf(fmaf(dy * rr, lw.y, lbv.y)) << 16);
      *(u32*)&hs[r][lane * 2] = pk;
    }
  }
  __syncthreads();

  const int l15 = lane & 15, quad = lane >> 4;
  int bl[4], ll[4];
  #pragma unroll
  for (int r = 0; r < 4; ++r) {
    int gr = row0 + wv * 16 + quad * 4 + r;
    bl[r] = gr / 200;
    ll[r] = gr - bl[r] * 200;
  }
  bf16x8 af[4];
  #pragma unroll
  for (int kst = 0; kst < 4; ++kst)
    af[kst] = *(const bf16x8*)&hs[wv * 16 + l15][kst * 32 + quad * 8];

  const float scale = 0.17677669529663687f;
  #pragma unroll
  for (int nt = 0; nt < 24; ++nt) {
    f32x4 acc = (f32x4){0.f, 0.f, 0.f, 0.f};
    const u16* wb = Wqkvs + ((size_t)(nt * 4) * 64 + lane) * 8;
    #pragma unroll
    for (int kst = 0; kst < 4; ++kst) {
      bf16x8 bfr = *(const bf16x8*)(wb + kst * 64 * 8);
      acc = __builtin_amdgcn_mfma_f32_16x16x32_bf16(af[kst], bfr, acc, 0, 0, 0);
    }
    const int col = (nt & 7) * 16 + l15;
    const int head = col >> 5, dk = col & 31;
    if (nt < 8) {
      float bb = bq[col];
      #pragma unroll
      for (int r = 0; r < 4; ++r)
        qo[((size_t)(bl[r] * 4 + head) * 200 + ll[r]) * 32 + dk] = f2bf((acc[r] + bb) * scale);
    } else if (nt < 16) {
      float bb = bk[col];
      #pragma unroll
      for (int r = 0; r < 4; ++r)
        ko[((size_t)(bl[r] * 4 + head) * 200 + ll[r]) * 32 + dk] = f2bf(acc[r] + bb);
    } else {
      float bb = bv[col];
      #pragma unroll
      for (int r = 0; r < 4; ++r)
        vo[((size_t)(bl[r] * 4 + head) * 200 + ll[r]) * 32 + dk] = f2bf(acc[r] + bb);
    }
  }
}

// ---------------- MFMA attention: one block per (b_local, head) ----------------
__global__ __launch_bounds__(256, 3)
void k_attn2(const u16* __restrict__ q, const u16* __restrict__ k,
             const u16* __restrict__ v, const int* __restrict__ seq,
             u16* __restrict__ attn) {
  __shared__ float smask[224];
  __shared__ __align__(16) u16 vt[32 * PVP];
  __shared__ __align__(16) u16 Pb[4][16 * PVP];
  const int tid = threadIdx.x;
  const int bl = blockIdx.x >> 2, head = blockIdx.x & 3;
  const int bh = blockIdx.x;
  const int lane = tid & 63, wv = tid >> 6;
  const int l15 = lane & 15, quad = lane >> 4;

  if (tid < 224)
    smask[tid] = (tid < 200 && seq[bl * 200 + tid] > 0) ? 0.f : -1e9f;
  // stage V^T into LDS: vt[dk][l]
  #pragma unroll 1
  for (int e = tid; e < 800; e += 256) {
    int l = e >> 2, g = (e & 3) * 8;
    uint4 pv = *(const uint4*)(v + ((size_t)bh * 200 + l) * 32 + g);
    const u16* pw = (const u16*)&pv;
    #pragma unroll
    for (int j = 0; j < 8; ++j) vt[(g + j) * PVP + l] = pw[j];
  }
  // zero V^T pad cols [200,232)
  #pragma unroll 1
  for (int e = tid; e < 1024; e += 256) {
    int rr = e >> 5, cc = 200 + (e & 31);
    vt[rr * PVP + cc] = 0;
  }
  __syncthreads();

  float msk[14];
  #pragma unroll
  for (int nt = 0; nt < 14; ++nt) msk[nt] = smask[nt * 16 + l15];

  const u16* qbase = q + (size_t)bh * 200 * 32;
  const u16* kbase = k + (size_t)bh * 200 * 32;
  u16* Pw = Pb[wv];

  #pragma unroll 1
  for (int mt = wv; mt < 13; mt += 4) {
    bf16x8 qf = *(const bf16x8*)(qbase + (mt * 16 + l15) * 32 + quad * 8);
    f32x4 s[14];
    #pragma unroll
    for (int nt = 0; nt < 14; ++nt) {
      bf16x8 kf = *(const bf16x8*)(kbase + (nt * 16 + l15) * 32 + quad * 8);
      s[nt] = __builtin_amdgcn_mfma_f32_16x16x32_bf16(qf, kf, (f32x4){0.f, 0.f, 0.f, 0.f}, 0, 0, 0);
    }
    // mask + row max
    float rmax[4] = {-1e30f, -1e30f, -1e30f, -1e30f};
    #pragma unroll
    for (int nt = 0; nt < 14; ++nt) {
      #pragma unroll
      for (int r = 0; r < 4; ++r) {
        s[nt][r] += msk[nt];
        rmax[r] = fmaxf(rmax[r], s[nt][r]);
      }
    }
    #pragma unroll
    for (int m = 1; m < 16; m <<= 1) {
      #pragma unroll
      for (int r = 0; r < 4; ++r) rmax[r] = fmaxf(rmax[r], __shfl_xor(rmax[r], m));
    }
    // exp + row sum
    float rsum[4] = {0.f, 0.f, 0.f, 0.f};
    #pragma unroll
    for (int nt = 0; nt < 14; ++nt) {
      #pragma unroll
      for (int r = 0; r < 4; ++r) {
        float p = __expf(s[nt][r] - rmax[r]);
        s[nt][r] = p;
        rsum[r] += p;
      }
    }
    #pragma unroll
    for (int m = 1; m < 16; m <<= 1) {
      #pragma unroll
      for (int r = 0; r < 4; ++r) rsum[r] += __shfl_xor(rsum[r], m);
    }
    float inv[4];
    #pragma unroll
    for (int r = 0; r < 4; ++r) inv[r] = 1.0f / rsum[r];
    // P -> wave-private LDS (bf16, unnormalized)
    #pragma unroll
    for (int nt = 0; nt < 14; ++nt) {
      #pragma unroll
      for (int r = 0; r < 4; ++r)
        Pw[(quad * 4 + r) * PVP + nt * 16 + l15] = f2bf(s[nt][r]);
    }
    __asm__ __volatile__("s_waitcnt lgkmcnt(0)" ::: "memory");
    // O = P @ V
    f32x4 o0 = (f32x4){0.f, 0.f, 0.f, 0.f}, o1 = (f32x4){0.f, 0.f, 0.f, 0.f};
    #pragma unroll
    for (int kst = 0; kst < 7; ++kst) {
      bf16x8 pf  = *(const bf16x8*)&Pw[l15 * PVP + kst * 32 + quad * 8];
      bf16x8 vf0 = *(const bf16x8*)&vt[l15 * PVP + kst * 32 + quad * 8];
      bf16x8 vf1 = *(const bf16x8*)&vt[(16 + l15) * PVP + kst * 32 + quad * 8];
      o0 = __builtin_amdgcn_mfma_f32_16x16x32_bf16(pf, vf0, o0, 0, 0, 0);
      o1 = __builtin_amdgcn_mfma_f32_16x16x32_bf16(pf, vf1, o1, 0, 0, 0);
    }
    #pragma unroll
    for (int r = 0; r < 4; ++r) {
      int row = mt * 16 + quad * 4 + r;
      if (row < 200) {
        u16* op = attn + ((size_t)bl * 200 + row) * 128 + head * 32;
        op[l15]      = f2bf(o0[r] * inv[r]);
        op[16 + l15] = f2bf(o1[r] * inv[r]);
      }
    }
  }
}

// ---------------- O-projection + residual (MFMA): x += a @ Wo + bo ----------------
__global__ __launch_bounds__(256, 4)
void k_oproj(const u16* __restrict__ a, const u16* __restrict__ Wos,
             const float* __restrict__ bo, float* __restrict__ x) {
  const int tid = threadIdx.x;
  const int lane = tid & 63, wv = tid >> 6;
  const int l15 = lane & 15, quad = lane >> 4;
  const size_t m0 = (size_t)blockIdx.x * 64 + wv * 16;
  f32x4 acc[8];
  #pragma unroll
  for (int i = 0; i < 8; ++i) acc[i] = (f32x4){0.f, 0.f, 0.f, 0.f};
  #pragma unroll
  for (int kst = 0; kst < 4; ++kst) {
    bf16x8 af = *(const bf16x8*)(a + (m0 + l15) * Dx + kst * 32 + quad * 8);
    const u16* wb = Wos + (kst * 64 + lane) * 8;
    #pragma unroll
    for (int nt = 0; nt < 8; ++nt) {
      bf16x8 bf = *(const bf16x8*)(wb + nt * (4 * 64 * 8));
      acc[nt] = __builtin_amdgcn_mfma_f32_16x16x32_bf16(af, bf, acc[nt], 0, 0, 0);
    }
  }
  #pragma unroll
  for (int nt = 0; nt < 8; ++nt) {
    int col = nt * 16 + l15;
    float bb = bo[col];
    #pragma unroll
    for (int r = 0; r < 4; ++r) {
      size_t idx = (m0 + quad * 4 + r) * Dx + col;
      x[idx] += acc[nt][r] + bb;
    }
  }
}

// ---------------- fused LN + FFN (MFMA): x += gelu(LN(x)@W1+b1)@W2 + b2 ----------------
__global__ __launch_bounds__(256, 2)
void k_ffn(float* __restrict__ x, const float* __restrict__ ln_w,
           const float* __restrict__ ln_b,
           const u16* __restrict__ W1s, const float* __restrict__ b1,
           const u16* __restrict__ W2s, const float* __restrict__ b2) {
  __shared__ u16 hs[64][LNP];
  __shared__ u16 ts[64][LNP];
  const int tid = threadIdx.x;
  const size_t row0 = (size_t)blockIdx.x * 64;
  const int lane = tid & 63, wv = tid >> 6;

  {
    float2 lw = *(const float2*)(ln_w + lane * 2);
    float2 lbv = *(const float2*)(ln_b + lane * 2);
    #pragma unroll 1
    for (int r = wv; r < 64; r += 4) {
      float2 v = *(const float2*)(x + (row0 + r) * Dx + lane * 2);
      float s = v.x + v.y;
      #pragma unroll
      for (int off = 32; off; off >>= 1) s += __shfl_down(s, off);
      float mu = __shfl(s, 0) * 0.0078125f;
      float dx = v.x - mu, dy = v.y - mu;
      float q = fmaf(dx, dx, dy * dy);
      #pragma unroll
      for (int off = 32; off; off >>= 1) q += __shfl_down(q, off);
      float rr = rsqrtf(fmaf(__shfl(q, 0), 0.0078125f, 1e-5f));
      u32 pk = (u32)f2bf(fmaf(dx * rr, lw.x, lbv.x)) |
               ((u32)f2bf(fmaf(dy * rr, lw.y, lbv.y)) << 16);
      *(u32*)&hs[r][lane * 2] = pk;
    }
  }
  __syncthreads();

  const int l15 = lane & 15, quad = lane >> 4;
  const int m0 = wv * 16;
  f32x4 acc2[8];
  #pragma unroll
  for (int i = 0; i < 8; ++i) acc2[i] = (f32x4){0.f, 0.f, 0.f, 0.f};

  #pragma unroll 1
  for (int ch = 0; ch < 4; ++ch) {
    f32x4 acc1[8];
    #pragma unroll
    for (int i = 0; i < 8; ++i) acc1[i] = (f32x4){0.f, 0.f, 0.f, 0.f};
    #pragma unroll
    for (int kst = 0; kst < 4; ++kst) {
      bf16x8 af = *(const bf16x8*)&hs[m0 + l15][kst * 32 + quad * 8];
      const u16* wb = W1s + (((ch * 8) * 4 + kst) * 64 + lane) * 8;
      #pragma unroll
      for (int nt = 0; nt < 8; ++nt) {
        bf16x8 bf = *(const bf16x8*)(wb + nt * (4 * 64 * 8));
        acc1[nt] = __builtin_amdgcn_mfma_f32_16x16x32_bf16(af, bf, acc1[nt], 0, 0, 0);
      }
    }
    __syncthreads();
    #pragma unroll
    for (int nt = 0; nt < 8; ++nt) {
      int col = nt * 16 + l15;
      float bb = b1[ch * 128 + col];
      #pragma unroll
      for (int r = 0; r < 4; ++r) {
        float v = acc1[nt][r] + bb;
        v = 0.5f * v * (1.0f + erff(v * 0.70710678118654752f));
        ts[m0 + quad * 4 + r][col] = f2bf(v);
      }
    }
    __syncthreads();
    #pragma unroll
    for (int kst = 0; kst < 4; ++kst) {
      bf16x8 af = *(const bf16x8*)&ts[m0 + l15][kst * 32 + quad * 8];
      const u16* wb = W2s + ((ch * 4 + kst) * 64 + lane) * 8;
      #pragma unroll
      for (int nt = 0; nt < 8; ++nt) {
        bf16x8 bf = *(const bf16x8*)(wb + nt * (16 * 64 * 8));
        acc2[nt] = __builtin_amdgcn_mfma_f32_16x16x32_bf16(af, bf, acc2[nt], 0, 0, 0);
      }
    }
  }
  #pragma unroll
  for (int nt = 0; nt < 8; ++nt) {
    int col = nt * 16 + l15;
    float bb = b2[col];
    #pragma unroll
    for (int r = 0; r < 4; ++r) {
      size_t idx = (row0 + m0 + quad * 4 + r) * Dx + col;
      x[idx] += acc2[nt][r] + bb;
    }
  }
}

// ---------------- final FC (MFMA, split-K 32) ----------------
__global__ __launch_bounds__(256, 4)
void k_fc(const float* __restrict__ x, const u16* __restrict__ fcWs,
          float* __restrict__ part) {
  const int tid = threadIdx.x;
  const int lane = tid & 63, wv = tid >> 6;
  const int l15 = lane & 15, quad = lane >> 4;
  const int m0 = blockIdx.x * 64 + wv * 16;
  const int ky = blockIdx.y;
  f32x4 acc[8];
  #pragma unroll
  for (int i = 0; i < 8; ++i) acc[i] = (f32x4){0.f, 0.f, 0.f, 0.f};
  const float* xp = x + (size_t)(m0 + l15) * 25600 + quad * 8;
  #pragma unroll 1
  for (int kst = ky * 25; kst < ky * 25 + 25; ++kst) {
    float4 xa = *(const float4*)(xp + kst * 32);
    float4 xb2 = *(const float4*)(xp + kst * 32 + 4);
    bf16x8 af;
    af[0] = (short)f2bf(xa.x);  af[1] = (short)f2bf(xa.y);
    af[2] = (short)f2bf(xa.z);  af[3] = (short)f2bf(xa.w);
    af[4] = (short)f2bf(xb2.x); af[5] = (short)f2bf(xb2.y);
    af[6] = (short)f2bf(xb2.z); af[7] = (short)f2bf(xb2.w);
    const u16* wb = fcWs + ((size_t)kst * 64 + lane) * 8;
    #pragma unroll
    for (int nt = 0; nt < 8; ++nt) {
      bf16x8 bf = *(const bf16x8*)(wb + (size_t)nt * (800 * 64 * 8));
      acc[nt] = __builtin_amdgcn_mfma_f32_16x16x32_bf16(af, bf, acc[nt], 0, 0, 0);
    }
  }
  float* pp = part + (size_t)ky * (Bx * Dx);
  #pragma unroll
  for (int nt = 0; nt < 8; ++nt) {
    #pragma unroll
    for (int r = 0; r < 4; ++r) {
      pp[(size_t)(m0 + quad * 4 + r) * Dx + nt * 16 + l15] = acc[nt][r];
    }
  }
}

__global__ void k_fcred(const float* __restrict__ part, const float* __restrict__ fcb,
                        float* __restrict__ out) {
  int i = blockIdx.x * 256 + threadIdx.x;
  float s = fcb[i & 127];
  #pragma unroll
  for (int k = 0; k < 32; ++k) s += part[(size_t)k * (Bx * Dx) + i];
  out[i] = s;
}

extern "C" void kernel_launch(void* const* d_in, const int* in_sizes, int n_in,
                              void* d_out, int out_size, void* d_ws, size_t ws_size,
                              hipStream_t stream) {
  const int*   seq  = (const int*)d_in[0];
  const float* tok  = (const float*)d_in[1];
  const float* pos  = (const float*)d_in[2];
  const float* Wq   = (const float*)d_in[3];
  const float* bq   = (const float*)d_in[4];
  const float* Wk   = (const float*)d_in[5];
  const float* bk   = (const float*)d_in[6];
  const float* Wv   = (const float*)d_in[7];
  const float* bv   = (const float*)d_in[8];
  const float* Wo   = (const float*)d_in[9];
  const float* bo   = (const float*)d_in[10];
  const float* ln1w = (const float*)d_in[11];
  const float* ln1b = (const float*)d_in[12];
  const float* ln2w = (const float*)d_in[13];
  const float* ln2b = (const float*)d_in[14];
  const float* W1   = (const float*)d_in[15];
  const float* b1   = (const float*)d_in[16];
  const float* W2   = (const float*)d_in[17];
  const float* b2   = (const float*)d_in[18];
  const float* fcW  = (const float*)d_in[19];
  const float* fcb  = (const float*)d_in[20];
  float* out = (float*)d_out;

  char* ws = (char*)d_ws;
  const size_t XB = (size_t)Mx * Dx * 4;        // 104,857,600 B
  const size_t WBSZ = 7340032;                  // converted-weight region

  // adaptive batch chunking: 4 equal bf16 regions of (Bx/nc)*51200 B after x
  int nc = 4;
  for (int t = 1; t <= 4; t <<= 1) {
    size_t qsz = (size_t)(Bx / t) * 51200;
    if (XB + 4 * qsz + WBSZ <= ws_size) { nc = t; break; }
  }
  const int BC = Bx / nc;                        // batches per chunk
  const size_t qsz = (size_t)BC * 51200;

  float* x    = (float*)ws;
  u16* qb     = (u16*)(ws + XB);
  u16* kb     = (u16*)(ws + XB + qsz);
  u16* vb     = (u16*)(ws + XB + 2 * qsz);
  u16* ab     = (u16*)(ws + XB + 3 * qsz);
  float* part = (float*)(ws + XB);               // aliases q/k (dead by k_fc)
  char* WB    = ws + XB + 4 * qsz;
  u16* W1s0   = (u16*)(WB);
  u16* W1s1   = (u16*)(WB + 131072);
  u16* W2s0   = (u16*)(WB + 262144);
  u16* W2s1   = (u16*)(WB + 393216);
  u16* Wos0   = (u16*)(WB + 524288);
  u16* Wos1   = (u16*)(WB + 557056);
  u16* Wqkvs0 = (u16*)(WB + 589824);
  u16* Wqkvs1 = (u16*)(WB + 688128);
  u16* fcWs   = (u16*)(WB + 786432);

  // weight conversion to fragment-ordered bf16
  k_cvt<<<32, 256, 0, stream>>>(W1, W1s0, FFx, 4);
  k_cvt<<<32, 256, 0, stream>>>(W1 + Dx * FFx, W1s1, FFx, 4);
  k_cvt<<<32, 256, 0, stream>>>(W2, W2s0, Dx, 16);
  k_cvt<<<32, 256, 0, stream>>>(W2 + FFx * Dx, W2s1, Dx, 16);
  k_cvt<<<8, 256, 0, stream>>>(Wo, Wos0, Dx, 4);
  k_cvt<<<8, 256, 0, stream>>>(Wo + Dx * Dx, Wos1, Dx, 4);
  k_cvt<<<8, 256, 0, stream>>>(Wq, Wqkvs0, Dx, 4);
  k_cvt<<<8, 256, 0, stream>>>(Wk, Wqkvs0 + 16384, Dx, 4);
  k_cvt<<<8, 256, 0, stream>>>(Wv, Wqkvs0 + 32768, Dx, 4);
  k_cvt<<<8, 256, 0, stream>>>(Wq + Dx * Dx, Wqkvs1, Dx, 4);
  k_cvt<<<8, 256, 0, stream>>>(Wk + Dx * Dx, Wqkvs1 + 16384, Dx, 4);
  k_cvt<<<8, 256, 0, stream>>>(Wv + Dx * Dx, Wqkvs1 + 32768, Dx, 4);
  k_cvt<<<1600, 256, 0, stream>>>(fcW, fcWs, Dx, 800);

  k_embed<<<25600, 256, 0, stream>>>(seq, tok, pos, x);
  const int cblk = BC * 200 / 64;   // 64-row blocks per chunk
  for (int i = 0; i < 2; ++i) {
    const u16* Wqkvs = (i == 0) ? Wqkvs0 : Wqkvs1;
    const u16* Wos   = (i == 0) ? Wos0 : Wos1;
    for (int c = 0; c < nc; ++c) {
      const float* xc = x + (size_t)c * BC * 200 * 128;
      k_qkv<<<cblk, 256, 0, stream>>>(xc, ln1w + i * Dx, ln1b + i * Dx, Wqkvs,
                                      bq + i * Dx, bk + i * Dx, bv + i * Dx,
                                      qb, kb, vb);
      k_attn2<<<BC * 4, 256, 0, stream>>>(qb, kb, vb, seq + (size_t)c * BC * 200, ab);
      k_oproj<<<cblk, 256, 0, stream>>>(ab, Wos, bo + i * Dx, (float*)xc);
    }
    k_ffn<<<3200, 256, 0, stream>>>(x, ln2w + i * Dx, ln2b + i * Dx,
                                    (i == 0) ? W1s0 : W1s1, b1 + i * FFx,
                                    (i == 0) ? W2s0 : W2s1, b2 + i * Dx);
  }
  k_fc<<<dim3(16, 32), 256, 0, stream>>>(x, fcWs, part);
  k_fcred<<<512, 256, 0, stream>>>(part, fcb, out);
}